// Round 3
// baseline (2668.131 us; speedup 1.0000x reference)
//
#include <hip/hip_runtime.h>

constexpr int PT_  = 500000;  // total params
constexpr int KT_  = 398;     // total bases
constexpr int KTP_ = 400;     // padded E row stride

// ws layout (floats):
//   E    [64*400]   @ 0       (zeroed; atomic accumulate, row-major [b][k])
//   NG   [64]       @ 25600   (||G[b]||^2, atomic)
//   NA   [64]       @ 25664   (||approx[b]||^2, atomic)
//   w    [398]      @ 25728
//   sRes [64]       @ 26126
//   nE   [64]       @ 26190   (||E[b]||^2)
//   ET   [400*64]   @ 26256   (E transposed, [k][b])

__global__ __launch_bounds__(256) void zero_kernel(float* __restrict__ p, int n) {
    int i = blockIdx.x * 256 + threadIdx.x;
    if (i < n) p[i] = 0.f;
}

// ---------- Kernel A: E = G @ B + ||G[b]||^2. No LDS, no barriers. ----------
// 512 thr = 8 waves; wave w owns b in [8w,8w+8); lane = k (KSLOT slots of 64).
// G loads wave-uniform -> scalar pipe; B loads coalesced 64-wide.
template <int KG, int KSLOT>
__global__ __launch_bounds__(512) void kernelA(const float* __restrict__ G,
                                               const float* __restrict__ Bg,
                                               int Pg, int poff, int koff,
                                               float* __restrict__ E,
                                               float* __restrict__ NG) {
    const int t    = threadIdx.x;
    const int wid  = __builtin_amdgcn_readfirstlane(t >> 6);  // 0..7, wave-uniform
    const int lane = t & 63;

    const int span = (Pg + gridDim.x - 1) / gridDim.x;
    const int p0   = blockIdx.x * span;
    const int p1   = (p0 + span < Pg) ? (p0 + span) : Pg;

    const float* gr[8];
#pragma unroll
    for (int i = 0; i < 8; i++) gr[i] = G + (size_t)(8 * wid + i) * PT_ + poff;

    float acc[8][KSLOT];
#pragma unroll
    for (int i = 0; i < 8; i++)
#pragma unroll
        for (int m = 0; m < KSLOT; m++) acc[i][m] = 0.f;

    const int   klast    = lane + 64 * (KSLOT - 1);
    const int   kclamp   = (klast < KG) ? klast : (KG - 1);
    const float lastmask = (klast < KG) ? 1.f : 0.f;

#pragma unroll 2
    for (int p = p0; p < p1; ++p) {
        const float* brow = Bg + (size_t)p * KG;
        float bv[KSLOT];
#pragma unroll
        for (int m = 0; m < KSLOT; m++) {
            if (64 * (m + 1) <= KG) bv[m] = brow[lane + 64 * m];     // full slot
            else                    bv[m] = brow[kclamp] * lastmask;  // masked slot
        }
        float g[8];
#pragma unroll
        for (int i = 0; i < 8; i++) g[i] = gr[i][p];   // wave-uniform -> s_load
#pragma unroll
        for (int i = 0; i < 8; i++)
#pragma unroll
            for (int m = 0; m < KSLOT; m++) acc[i][m] += g[i] * bv[m];
    }

    // ||G[b]||^2 via vectorized lane-strided pass (L2-hot)
    float ng[8];
#pragma unroll
    for (int i = 0; i < 8; i++) ng[i] = 0.f;
    for (int pp = p0 + lane; pp < p1; pp += 64) {
#pragma unroll
        for (int i = 0; i < 8; i++) { float v = gr[i][pp]; ng[i] += v * v; }
    }
#pragma unroll
    for (int i = 0; i < 8; i++) {
        float s = ng[i];
#pragma unroll
        for (int off = 32; off > 0; off >>= 1) s += __shfl_down(s, off, 64);
        if (lane == 0) atomicAdd(&NG[8 * wid + i], s);
    }

    // E accumulate: coalesced (lanes -> consecutive k)
#pragma unroll
    for (int i = 0; i < 8; i++)
#pragma unroll
        for (int m = 0; m < KSLOT; m++) {
            int k = lane + 64 * m;
            if (k < KG) atomicAdd(&E[(8 * wid + i) * KTP_ + koff + k], acc[i][m]);
        }
}

// ---------- Kernel C1: ET transpose + embedding norms + out0 ----------
__global__ __launch_bounds__(256) void kernelC1(const float* __restrict__ E,
                                                float* __restrict__ ET,
                                                float* __restrict__ nE,
                                                float* __restrict__ out0) {
    __shared__ float red[256];
    __shared__ float sEmb[64];
    const int t = threadIdx.x;
    const int b = t & 63, part = t >> 6;
    // transpose slice: 50 k-rows per block
    const int k0 = 50 * blockIdx.x;
    for (int k = k0 + part; k < k0 + 50; k += 4) ET[k * 64 + b] = E[b * KTP_ + k];
    if (blockIdx.x != 0) return;

    float acc = 0.f;
    for (int k = part * 100; k < part * 100 + 100; k++) {
        float v = E[b * KTP_ + k];
        acc += v * v;
    }
    red[part * 64 + b] = acc;
    __syncthreads();
    if (t < 64) {
        float ne = red[t] + red[64 + t] + red[128 + t] + red[192 + t];
        nE[t]    = ne;
        sEmb[t]  = fminf(1.f / sqrtf(fmaxf(ne, 0.f)), 1.f);  // CLIP0=1
    }
    __syncthreads();
    for (int k = t; k < KT_; k += 256) {
        float e0 = 0.f;
        for (int bb = 0; bb < 64; bb++) e0 += sEmb[bb] * E[bb * KTP_ + k];
        out0[k] = e0 * (1.f / 64.f);
    }
}

// ---------- Kernel B: ||approx[b]||^2. lane = p, wave owns 16 b. ----------
template <int KG>
__global__ __launch_bounds__(256) void kernelB(const float* __restrict__ Bg,
                                               const float* __restrict__ ET,
                                               int Pg, int koff,
                                               float* __restrict__ NA) {
    constexpr int LDB = KG + 1;     // odd -> conflict-free lane-strided reads
    __shared__ float Bs[64 * LDB];
    const int t    = threadIdx.x;
    const int wid  = __builtin_amdgcn_readfirstlane(t >> 6);  // 0..3
    const int lane = t & 63;
    const int nT   = (Pg + 63) >> 6;

    float pn[16];
#pragma unroll
    for (int i = 0; i < 16; i++) pn[i] = 0.f;

    const float* ETg = ET + (size_t)koff * 64 + wid * 16;  // wave-uniform base

    for (int tile = blockIdx.x; tile < nT; tile += gridDim.x) {
        const int pbase = tile * 64;
        __syncthreads();
#pragma unroll
        for (int rr = 0; rr < 16; rr++) {
            int  r  = 16 * wid + rr;
            int  p  = pbase + r;
            bool ok = (p < Pg);
            const float* brow = Bg + (size_t)p * KG;
            for (int c = lane; c < KG; c += 64)
                Bs[r * LDB + c] = ok ? brow[c] : 0.f;
        }
        __syncthreads();
        float accv[16];
#pragma unroll
        for (int i = 0; i < 16; i++) accv[i] = 0.f;
        for (int k = 0; k < KG; k++) {
            float        bval = Bs[lane * LDB + k];
            const float* ev   = ETg + (size_t)k * 64;   // wave-uniform -> s_load
#pragma unroll
            for (int i = 0; i < 16; i++) accv[i] += ev[i] * bval;
        }
#pragma unroll
        for (int i = 0; i < 16; i++) pn[i] += accv[i] * accv[i];
    }

#pragma unroll
    for (int i = 0; i < 16; i++) {
        float s = pn[i];
#pragma unroll
        for (int off = 32; off > 0; off >>= 1) s += __shfl_down(s, off, 64);
        if (lane == 0) atomicAdd(&NA[16 * wid + i], s);
    }
}

// ---------- Kernel C2: residual scales + w ----------
__global__ __launch_bounds__(256) void kernelC2(const float* __restrict__ NG,
                                                const float* __restrict__ NA,
                                                const float* __restrict__ nE,
                                                const float* __restrict__ E,
                                                float* __restrict__ w,
                                                float* __restrict__ sRes) {
    __shared__ float sS[64];
    const int t = threadIdx.x;
    if (t < 64) {
        // <G[b],approx[b]> == ||E[b]||^2 exactly (E = G B)
        float rn2 = NG[t] - 2.f * nE[t] + NA[t];
        float sv  = fminf(1.f / sqrtf(fmaxf(rn2, 0.f)), 1.f);  // CLIP1=1
        sS[t]     = sv;
        sRes[t]   = sv;
    }
    __syncthreads();
    for (int k = t; k < KT_; k += 256) {
        float wv = 0.f;
        for (int bb = 0; bb < 64; bb++) wv += sS[bb] * E[bb * KTP_ + k];
        w[k] = wv;
    }
}

// ---------- Kernel D: out1 = (sum_b s_b G[b,p] - sum_k w[k] B[p,k])/64 ; out2 = mean_b G ----------
template <int KG>
__global__ __launch_bounds__(256) void kernelD(const float* __restrict__ G,
                                               const float* __restrict__ Bg,
                                               const float* __restrict__ w,
                                               const float* __restrict__ sRes,
                                               int Pg, int poff, int koff,
                                               float* __restrict__ out1, float* __restrict__ out2) {
    constexpr int LDB = KG + 1;
    constexpr int KQ  = (KG + 3) / 4;
    __shared__ float Bt[64 * LDB];
    __shared__ float wS[KG];
    __shared__ float sS[64];
    __shared__ float redA[256], redT[256], redD[256];
    const int t    = threadIdx.x;
    const int pidx = t & 63, part = t >> 6;
    const int p0   = blockIdx.x * 64;

    for (int k = t; k < KG; k += 256) wS[k] = w[koff + k];
    if (t < 64) sS[t] = sRes[t];
    for (int idx = t; idx < 64 * KG; idx += 256) {
        int r = idx / KG, c = idx - r * KG;
        int p = p0 + r;
        Bt[r * LDB + c] = (p < Pg) ? Bg[(size_t)p * KG + c] : 0.f;
    }
    __syncthreads();

    const int p = p0 + pidx;
    float a = 0.f, t2 = 0.f, dot = 0.f;
    if (p < Pg) {
#pragma unroll
        for (int bi = 0; bi < 16; bi++) {
            int   b = part * 16 + bi;
            float g = G[(size_t)b * PT_ + poff + p];
            a  += sS[b] * g;
            t2 += g;
        }
        const int k1 = (part * KQ + KQ < KG) ? (part * KQ + KQ) : KG;
        for (int k = part * KQ; k < k1; k++) dot += wS[k] * Bt[pidx * LDB + k];
    }
    redA[t] = a; redT[t] = t2; redD[t] = dot;
    __syncthreads();
    if (part == 0 && p < Pg) {
        float A = redA[t] + redA[64 + t] + redA[128 + t] + redA[192 + t];
        float T = redT[t] + redT[64 + t] + redT[128 + t] + redT[192 + t];
        float D = redD[t] + redD[64 + t] + redD[128 + t] + redD[192 + t];
        out1[poff + p] = (A - D) * (1.f / 64.f);
        out2[poff + p] = T * (1.f / 64.f);
    }
}

extern "C" void kernel_launch(void* const* d_in, const int* in_sizes, int n_in,
                              void* d_out, int out_size, void* d_ws, size_t ws_size,
                              hipStream_t stream) {
    const float* G  = (const float*)d_in[0];
    const float* B0 = (const float*)d_in[1];
    const float* B1 = (const float*)d_in[2];
    const float* B2 = (const float*)d_in[3];
    float* out  = (float*)d_out;
    float* out0 = out;                  // [398]
    float* out1 = out + KT_;            // [500000]
    float* out2 = out + KT_ + PT_;      // [500000]

    float* ws = (float*)d_ws;
    float* E  = ws;                     // 25600
    float* NG = ws + 25600;             // 64
    float* NA = NG + 64;                // 64
    float* w  = NA + 64;                // 398
    float* sR = w + KT_;                // 64
    float* nE = sR + 64;                // 64
    float* ET = ws + 26256;             // 25600

    zero_kernel<<<101, 256, 0, stream>>>(E, 25728);  // E + NG + NA

    // Pass A: no-LDS barrier-free GEMM; 512 blocks x 512 thr = 4 waves/SIMD
    kernelA<104, 2><<<512, 512, 0, stream>>>(G, B0, 100000, 0,      0,   E, NG);
    kernelA<156, 3><<<512, 512, 0, stream>>>(G, B1, 225000, 100000, 104, E, NG);
    kernelA<138, 3><<<512, 512, 0, stream>>>(G, B2, 175000, 325000, 260, E, NG);

    // C1: ET transpose (8 blocks) + norms/out0 (block 0)
    kernelC1<<<8, 256, 0, stream>>>(E, ET, nE, out0);

    // Pass B: approx norms
    kernelB<104><<<768, 256, 0, stream>>>(B0, ET, 100000, 0,   NA);
    kernelB<156><<<768, 256, 0, stream>>>(B1, ET, 225000, 104, NA);
    kernelB<138><<<768, 256, 0, stream>>>(B2, ET, 175000, 260, NA);

    // C2: scales + w
    kernelC2<<<1, 256, 0, stream>>>(NG, NA, nE, E, w, sR);

    // Pass D
    kernelD<104><<<(100000 + 63) / 64, 256, 0, stream>>>(G, B0, w, sR, 100000, 0,      0,   out1, out2);
    kernelD<156><<<(225000 + 63) / 64, 256, 0, stream>>>(G, B1, w, sR, 225000, 100000, 104, out1, out2);
    kernelD<138><<<(175000 + 63) / 64, 256, 0, stream>>>(G, B2, w, sR, 175000, 325000, 260, out1, out2);
}